// Round 4
// baseline (470.419 us; speedup 1.0000x reference)
//
#include <hip/hip_runtime.h>
#include <math.h>

#define B_DIM 16
#define A_DIM 1024
#define V_DIM 512
#define D_DIM 512
#define NEGV  (-1e30f)

typedef short bf16x8 __attribute__((ext_vector_type(8)));
typedef float floatx4 __attribute__((ext_vector_type(4)));

// round-to-nearest-even fp32 -> bf16
__device__ __forceinline__ short bf16_rne(float f) {
    unsigned u = __float_as_uint(f);
    return (short)((u + 0x7fffu + ((u >> 16) & 1u)) >> 16);
}

// ---------------------------------------------------------------------------
// Merged elementwise fp32 -> bf16 for three segments (8 elems/thread).
// ---------------------------------------------------------------------------
__global__ __launch_bounds__(256) void cvt3_bf16_kernel(
    const float* __restrict__ in0, unsigned short* __restrict__ out0, int nb0,
    const float* __restrict__ in1, unsigned short* __restrict__ out1, int nb1,
    const float* __restrict__ in2, unsigned short* __restrict__ out2)
{
    int blk = blockIdx.x;
    const float* in; unsigned short* out;
    if (blk < nb0)              { in = in0; out = out0; }
    else if (blk < nb0 + nb1)   { in = in1; out = out1; blk -= nb0; }
    else                        { in = in2; out = out2; blk -= nb0 + nb1; }
    const int i = blk * 256 + threadIdx.x;
    float4 u = ((const float4*)in)[2*i];
    float4 v = ((const float4*)in)[2*i + 1];
    bf16x8 h;
    h[0]=bf16_rne(u.x); h[1]=bf16_rne(u.y); h[2]=bf16_rne(u.z); h[3]=bf16_rne(u.w);
    h[4]=bf16_rne(v.x); h[5]=bf16_rne(v.y); h[6]=bf16_rne(v.z); h[7]=bf16_rne(v.w);
    *(bf16x8*)(out + (size_t)i * 8) = h;
}

// ---------------------------------------------------------------------------
// bf16 MFMA NT GEMM with register-prefetch K-pipeline. 128x128 tile, BK=32.
// ---------------------------------------------------------------------------
__global__ __launch_bounds__(256) void gemm_bf16_nt(
    const unsigned short* __restrict__ Ag, const unsigned short* __restrict__ Bg,
    const float* __restrict__ bias, float* __restrict__ Cg,
    int M, int N, int K, size_t strA, size_t strB, size_t strC)
{
    __shared__ __align__(16) unsigned short lA[8*64*8];   // 8 KB
    __shared__ __align__(16) unsigned short lB[8*64*8];

    const unsigned short* Ab = Ag + (size_t)blockIdx.z * strA;
    const unsigned short* Bb = Bg + (size_t)blockIdx.z * strB;
    float*                Cb = Cg + (size_t)blockIdx.z * strC;

    const int m0 = blockIdx.y * 128;
    const int n0 = blockIdx.x * 128;
    const int tid = threadIdx.x, lane = tid & 63;
    const int w = tid >> 6, wy = w >> 1, wx = w & 1;

    const int u0 = tid, u1 = tid + 256;
    const int r_u0 = ((u0 >> 6) << 4) + (u0 & 15), k_u0 = ((u0 >> 4) & 3) * 8;
    const int r_u1 = ((u1 >> 6) << 4) + (u1 & 15), k_u1 = ((u1 >> 4) & 3) * 8;

    const unsigned short* gA0 = Ab + (size_t)(m0 + r_u0) * K + k_u0;
    const unsigned short* gA1 = Ab + (size_t)(m0 + r_u1) * K + k_u1;
    const unsigned short* gB0 = Bb + (size_t)(n0 + r_u0) * K + k_u0;
    const unsigned short* gB1 = Bb + (size_t)(n0 + r_u1) * K + k_u1;

    floatx4 acc[4][4];
    #pragma unroll
    for (int i = 0; i < 4; ++i)
        #pragma unroll
        for (int j = 0; j < 4; ++j) acc[i][j] = (floatx4){0.f, 0.f, 0.f, 0.f};

    bf16x8 a0 = *(const bf16x8*)(gA0);
    bf16x8 a1 = *(const bf16x8*)(gA1);
    bf16x8 b0 = *(const bf16x8*)(gB0);
    bf16x8 b1 = *(const bf16x8*)(gB1);

    for (int k0 = 0; k0 < K; k0 += 32) {
        __syncthreads();
        *(bf16x8*)&lA[(size_t)u0 * 8] = a0;
        *(bf16x8*)&lA[(size_t)u1 * 8] = a1;
        *(bf16x8*)&lB[(size_t)u0 * 8] = b0;
        *(bf16x8*)&lB[(size_t)u1 * 8] = b1;
        __syncthreads();

        if (k0 + 32 < K) {
            a0 = *(const bf16x8*)(gA0 + k0 + 32);
            a1 = *(const bf16x8*)(gA1 + k0 + 32);
            b0 = *(const bf16x8*)(gB0 + k0 + 32);
            b1 = *(const bf16x8*)(gB1 + k0 + 32);
        }

        bf16x8 fa[4], fb[4];
        #pragma unroll
        for (int t = 0; t < 4; ++t) {
            fa[t] = *(const bf16x8*)&lA[(((wy*4 + t)*64) + lane) * 8];
            fb[t] = *(const bf16x8*)&lB[(((wx*4 + t)*64) + lane) * 8];
        }
        #pragma unroll
        for (int i = 0; i < 4; ++i)
            #pragma unroll
            for (int j = 0; j < 4; ++j)
                acc[i][j] = __builtin_amdgcn_mfma_f32_16x16x32_bf16(fa[i], fb[j], acc[i][j], 0, 0, 0);
    }

    const int q = lane >> 4, c = lane & 15;
    #pragma unroll
    for (int i = 0; i < 4; ++i)
        #pragma unroll
        for (int j = 0; j < 4; ++j) {
            const int n = n0 + (wx*4 + j)*16 + c;
            const float bv = bias ? bias[n] : 0.f;
            #pragma unroll
            for (int r = 0; r < 4; ++r) {
                const int m = m0 + (wy*4 + i)*16 + q*4 + r;
                Cb[(size_t)m * N + n] = acc[i][j][r] + bv;
            }
        }
}

// ---------------------------------------------------------------------------
// Row L2-normalize fp32 -> bf16. One wave/row (512 cols).
// ---------------------------------------------------------------------------
__global__ __launch_bounds__(256) void rownorm_cvt_kernel(
    const float* __restrict__ in, unsigned short* __restrict__ out)
{
    const int wave = threadIdx.x >> 6;
    const int lane = threadIdx.x & 63;
    const size_t r = (size_t)blockIdx.x * 4 + wave;
    const float* p = in + r * D_DIM + lane * 8;
    float4 u = *(const float4*)p;
    float4 w = *(const float4*)(p + 4);
    float ss = u.x*u.x + u.y*u.y + u.z*u.z + u.w*u.w
             + w.x*w.x + w.y*w.y + w.z*w.z + w.w*w.w;
    #pragma unroll
    for (int m = 1; m < 64; m <<= 1) ss += __shfl_xor(ss, m, 64);
    const float inv = 1.0f / fmaxf(sqrtf(ss), 1e-12f);
    bf16x8 h;
    h[0]=bf16_rne(u.x*inv); h[1]=bf16_rne(u.y*inv); h[2]=bf16_rne(u.z*inv); h[3]=bf16_rne(u.w*inv);
    h[4]=bf16_rne(w.x*inv); h[5]=bf16_rne(w.y*inv); h[6]=bf16_rne(w.z*inv); h[7]=bf16_rne(w.w*inv);
    *(bf16x8*)(out + r * D_DIM + lane * 8) = h;
}

// ---------------------------------------------------------------------------
// DPP helper (wave64). 0x138 = wave_shr:1 (lane l <- l-1; lane 0 keeps oldv
// with bound_ctrl=false). Verified in prior rounds.
// ---------------------------------------------------------------------------
template <int CTRL, int RMASK>
__device__ __forceinline__ float fdpp(float oldv, float src) {
    int r = __builtin_amdgcn_update_dpp(
        __float_as_int(oldv), __float_as_int(src), CTRL, RMASK, 0xF, false);
    return __int_as_float(r);
}

// ---------------------------------------------------------------------------
// Fused: row softmax -> Pbf (bf16) + skewed fp32 copy of the raw sim row.
// skew[r][(c + ((r&1023)>>2)) & 511] = sim[r][c]: the 256-lane DTW wavefront
// (4 rows/lane, shift = global lane id) then reads lane-uniform column t&511.
// ---------------------------------------------------------------------------
__global__ __launch_bounds__(256) void softmax_skew_kernel(
    const float* __restrict__ sim, unsigned short* __restrict__ Pbf,
    float* __restrict__ skew)
{
    const int wave = threadIdx.x >> 6;
    const int lane = threadIdx.x & 63;
    const size_t r = (size_t)blockIdx.x * 4 + wave;
    const float* p = sim + r * V_DIM + lane * 8;
    float4 u = *(const float4*)p;
    float4 w = *(const float4*)(p + 4);
    float s[8] = {u.x,u.y,u.z,u.w,w.x,w.y,w.z,w.w};

    float m = s[0];
    #pragma unroll
    for (int k = 1; k < 8; ++k) m = fmaxf(m, s[k]);
    #pragma unroll
    for (int t = 1; t < 64; t <<= 1) m = fmaxf(m, __shfl_xor(m, t, 64));

    const float L2E = 1.44269504f;
    float ex[8];
    float e = 0.f;
    #pragma unroll
    for (int k = 0; k < 8; ++k) { ex[k] = exp2f((s[k] - m) * L2E); e += ex[k]; }
    #pragma unroll
    for (int t = 1; t < 64; t <<= 1) e += __shfl_xor(e, t, 64);
    const float ri = 1.0f / e;

    bf16x8 h;
    #pragma unroll
    for (int k = 0; k < 8; ++k) h[k] = bf16_rne(ex[k] * ri);
    *(bf16x8*)(Pbf + r * V_DIM + lane * 8) = h;

    // skewed raw-sim copy; rotation is row-uniform, writes contiguous mod 512
    const int sh = ((int)r & 1023) >> 2;     // = global lane id in DTW (0..255)
    float* Sk = skew + r * V_DIM;
    const int base = lane * 8 + sh;
    #pragma unroll
    for (int k = 0; k < 8; ++k) Sk[(base + k) & 511] = s[k];
}

// ---------------------------------------------------------------------------
// Batched 32x32 transpose + cvt: video[b][v][d] fp32 -> vT[b][d][v] bf16.
// ---------------------------------------------------------------------------
__global__ __launch_bounds__(256) void transpose_cvt_kernel(
    const float* __restrict__ in, unsigned short* __restrict__ out)
{
    __shared__ float t[32][33];
    const int b = blockIdx.z;
    const int v0 = blockIdx.y * 32, d0 = blockIdx.x * 32;
    const int x = threadIdx.x & 31, y0 = (threadIdx.x >> 5) * 4;
    const float* I = in + ((size_t)b * V_DIM + v0) * D_DIM + d0;
    #pragma unroll
    for (int r = 0; r < 4; ++r) t[y0 + r][x] = I[(size_t)(y0 + r) * D_DIM + x];
    __syncthreads();
    unsigned short* O = out + ((size_t)b * D_DIM + d0) * V_DIM + v0;
    #pragma unroll
    for (int r = 0; r < 4; ++r) O[(size_t)(y0 + r) * V_DIM + x] = (unsigned short)bf16_rne(t[x][y0 + r]);
}

// ---------------------------------------------------------------------------
// Fused PV GEMM + 256-lane wavefront DTW.
// DTW (blocks 0..15): all 4 waves form one 256-lane systolic array, 4 rows
// per lane (1024 rows = 1 band). Lane g computes col j = t - g at step t.
// Cross-wave handoff (lane63 bottom -> next wave lane0 up/diag) via 2-entry
// parity LDS slots + raw s_barrier per step (no vmcnt drain, so global
// prefetch stays in flight). Parity + barrier ordering makes the slot
// overwrite (step t+2) race-free vs the read (step t).
// ---------------------------------------------------------------------------
__global__ __launch_bounds__(256) void pv_dtw_kernel(
    const unsigned short* __restrict__ Pbf, const unsigned short* __restrict__ vTb,
    const float* __restrict__ skew, float* __restrict__ out_aligned,
    float* __restrict__ out_score)
{
    __shared__ __align__(16) unsigned short lA[8*64*8];
    __shared__ __align__(16) unsigned short lB[8*64*8];

    if (blockIdx.x < 16) {
        // ---------------- DTW path (all 256 threads) ----------------
        const int b = blockIdx.x;
        const int tid  = threadIdx.x;        // == global systolic lane 0..255
        const int lane = tid & 63;
        const int wv   = tid >> 6;
        float* bot = (float*)lA;             // 8 floats: [wave][parity]
        float* bot_my = bot + wv * 2;
        const float* bot_up = bot + (wv > 0 ? (wv - 1) * 2 : 0);
        if (tid < 8) bot[tid] = NEGV;
        __syncthreads();

        const float* R0 = skew + ((size_t)(b * 1024 + tid * 4)) * 512;
        const float* R1 = R0 + 512;
        const float* R2 = R0 + 1024;
        const float* R3 = R0 + 1536;

        float dp[4] = {NEGV, NEGV, NEGV, NEGV};
        float upC = NEGV;
        float upL = (tid == 0) ? 0.0f : NEGV;
        int   t_  = 0;

        float4 bA[4][2], bB[4][2];
        bA[0][0] = *(const float4*)(R0);     bA[0][1] = *(const float4*)(R0 + 4);
        bA[1][0] = *(const float4*)(R1);     bA[1][1] = *(const float4*)(R1 + 4);
        bA[2][0] = *(const float4*)(R2);     bA[2][1] = *(const float4*)(R2 + 4);
        bA[3][0] = *(const float4*)(R3);     bA[3][1] = *(const float4*)(R3 + 4);
        bB[0][0] = *(const float4*)(R0 + 8); bB[0][1] = *(const float4*)(R0 + 12);
        bB[1][0] = *(const float4*)(R1 + 8); bB[1][1] = *(const float4*)(R1 + 12);
        bB[2][0] = *(const float4*)(R2 + 8); bB[2][1] = *(const float4*)(R2 + 12);
        bB[3][0] = *(const float4*)(R3 + 8); bB[3][1] = *(const float4*)(R3 + 12);

// one systolic step: 4-cell chain, bottom handoff, raw barrier, refill up regs
#define DTW_CELLS(CV0, CV1, CV2, CV3)                                         \
        {                                                                     \
            const unsigned jj = (unsigned)t_ - (unsigned)tid;                 \
            if (jj < 512u) {                                                  \
                float u = upC, g = upL, old, nd;                              \
                old = dp[0]; nd = (CV0) + fmaxf(fmaxf(u, dp[0]), g); dp[0] = nd; g = old; u = nd; \
                old = dp[1]; nd = (CV1) + fmaxf(fmaxf(u, dp[1]), g); dp[1] = nd; g = old; u = nd; \
                old = dp[2]; nd = (CV2) + fmaxf(fmaxf(u, dp[2]), g); dp[2] = nd; g = old; u = nd; \
                old = dp[3]; nd = (CV3) + fmaxf(fmaxf(u, dp[3]), g); dp[3] = nd;                  \
            }                                                                 \
            if (lane == 63) bot_my[t_ & 1] = dp[3];                           \
            asm volatile("s_waitcnt lgkmcnt(0)" ::: "memory");                \
            __builtin_amdgcn_s_barrier();                                     \
            asm volatile("" ::: "memory");                                    \
            {                                                                 \
                float fill = NEGV;                                            \
                if (wv > 0) fill = bot_up[t_ & 1];                            \
                upL = upC;                                                    \
                upC = fdpp<0x138, 0xF>(fill, dp[3]);                          \
            }                                                                 \
            ++t_;                                                             \
        }

        #pragma unroll 1
        for (int tg = 0; tg < 768; tg += 16) {
            // 8 steps on bufA (cols tg..tg+7)
            DTW_CELLS(bA[0][0].x, bA[1][0].x, bA[2][0].x, bA[3][0].x)
            DTW_CELLS(bA[0][0].y, bA[1][0].y, bA[2][0].y, bA[3][0].y)
            DTW_CELLS(bA[0][0].z, bA[1][0].z, bA[2][0].z, bA[3][0].z)
            DTW_CELLS(bA[0][0].w, bA[1][0].w, bA[2][0].w, bA[3][0].w)
            DTW_CELLS(bA[0][1].x, bA[1][1].x, bA[2][1].x, bA[3][1].x)
            DTW_CELLS(bA[0][1].y, bA[1][1].y, bA[2][1].y, bA[3][1].y)
            DTW_CELLS(bA[0][1].z, bA[1][1].z, bA[2][1].z, bA[3][1].z)
            DTW_CELLS(bA[0][1].w, bA[1][1].w, bA[2][1].w, bA[3][1].w)
            {   // refill bufA <- cols (tg+16), used 8 steps from now
                const int off = (tg + 16) & 511;
                bA[0][0] = *(const float4*)(R0 + off); bA[0][1] = *(const float4*)(R0 + off + 4);
                bA[1][0] = *(const float4*)(R1 + off); bA[1][1] = *(const float4*)(R1 + off + 4);
                bA[2][0] = *(const float4*)(R2 + off); bA[2][1] = *(const float4*)(R2 + off + 4);
                bA[3][0] = *(const float4*)(R3 + off); bA[3][1] = *(const float4*)(R3 + off + 4);
            }
            // 8 steps on bufB (cols tg+8..tg+15)
            DTW_CELLS(bB[0][0].x, bB[1][0].x, bB[2][0].x, bB[3][0].x)
            DTW_CELLS(bB[0][0].y, bB[1][0].y, bB[2][0].y, bB[3][0].y)
            DTW_CELLS(bB[0][0].z, bB[1][0].z, bB[2][0].z, bB[3][0].z)
            DTW_CELLS(bB[0][0].w, bB[1][0].w, bB[2][0].w, bB[3][0].w)
            DTW_CELLS(bB[0][1].x, bB[1][1].x, bB[2][1].x, bB[3][1].x)
            DTW_CELLS(bB[0][1].y, bB[1][1].y, bB[2][1].y, bB[3][1].y)
            DTW_CELLS(bB[0][1].z, bB[1][1].z, bB[2][1].z, bB[3][1].z)
            DTW_CELLS(bB[0][1].w, bB[1][1].w, bB[2][1].w, bB[3][1].w)
            {   // refill bufB <- cols (tg+24)
                const int off = (tg + 24) & 511;
                bB[0][0] = *(const float4*)(R0 + off); bB[0][1] = *(const float4*)(R0 + off + 4);
                bB[1][0] = *(const float4*)(R1 + off); bB[1][1] = *(const float4*)(R1 + off + 4);
                bB[2][0] = *(const float4*)(R2 + off); bB[2][1] = *(const float4*)(R2 + off + 4);
                bB[3][0] = *(const float4*)(R3 + off); bB[3][1] = *(const float4*)(R3 + off + 4);
            }
        }
#undef DTW_CELLS
        if (tid == 255) out_score[b] = dp[3];
        return;
    }

    // ---------------- PV GEMM path ----------------
    const int bid = blockIdx.x - 16;
    const int n0 = (bid & 3) * 128;          // D/128 = 4
    const int m0 = ((bid >> 2) & 7) * 128;   // A/128 = 8
    const int bz = bid >> 5;                 // 16 batches
    const int K = V_DIM, N = D_DIM;

    const unsigned short* Ab = Pbf + (size_t)bz * A_DIM * V_DIM;
    const unsigned short* Bb = vTb + (size_t)bz * V_DIM * D_DIM;
    float*                Cb = out_aligned + (size_t)bz * A_DIM * D_DIM;

    const int tid = threadIdx.x, lane = tid & 63;
    const int w = tid >> 6, wy = w >> 1, wx = w & 1;
    const int u0 = tid, u1 = tid + 256;
    const int r_u0 = ((u0 >> 6) << 4) + (u0 & 15), k_u0 = ((u0 >> 4) & 3) * 8;
    const int r_u1 = ((u1 >> 6) << 4) + (u1 & 15), k_u1 = ((u1 >> 4) & 3) * 8;

    const unsigned short* gA0 = Ab + (size_t)(m0 + r_u0) * K + k_u0;
    const unsigned short* gA1 = Ab + (size_t)(m0 + r_u1) * K + k_u1;
    const unsigned short* gB0 = Bb + (size_t)(n0 + r_u0) * K + k_u0;
    const unsigned short* gB1 = Bb + (size_t)(n0 + r_u1) * K + k_u1;

    floatx4 acc[4][4];
    #pragma unroll
    for (int i = 0; i < 4; ++i)
        #pragma unroll
        for (int j = 0; j < 4; ++j) acc[i][j] = (floatx4){0.f, 0.f, 0.f, 0.f};

    bf16x8 a0 = *(const bf16x8*)(gA0);
    bf16x8 a1 = *(const bf16x8*)(gA1);
    bf16x8 b0 = *(const bf16x8*)(gB0);
    bf16x8 b1 = *(const bf16x8*)(gB1);

    for (int k0 = 0; k0 < K; k0 += 32) {
        __syncthreads();
        *(bf16x8*)&lA[(size_t)u0 * 8] = a0;
        *(bf16x8*)&lA[(size_t)u1 * 8] = a1;
        *(bf16x8*)&lB[(size_t)u0 * 8] = b0;
        *(bf16x8*)&lB[(size_t)u1 * 8] = b1;
        __syncthreads();
        if (k0 + 32 < K) {
            a0 = *(const bf16x8*)(gA0 + k0 + 32);
            a1 = *(const bf16x8*)(gA1 + k0 + 32);
            b0 = *(const bf16x8*)(gB0 + k0 + 32);
            b1 = *(const bf16x8*)(gB1 + k0 + 32);
        }
        bf16x8 fa[4], fb[4];
        #pragma unroll
        for (int t = 0; t < 4; ++t) {
            fa[t] = *(const bf16x8*)&lA[(((wy*4 + t)*64) + lane) * 8];
            fb[t] = *(const bf16x8*)&lB[(((wx*4 + t)*64) + lane) * 8];
        }
        #pragma unroll
        for (int i = 0; i < 4; ++i)
            #pragma unroll
            for (int j = 0; j < 4; ++j)
                acc[i][j] = __builtin_amdgcn_mfma_f32_16x16x32_bf16(fa[i], fb[j], acc[i][j], 0, 0, 0);
    }

    const int q = lane >> 4, c = lane & 15;
    #pragma unroll
    for (int i = 0; i < 4; ++i)
        #pragma unroll
        for (int j = 0; j < 4; ++j) {
            const int n = n0 + (wx*4 + j)*16 + c;
            #pragma unroll
            for (int r = 0; r < 4; ++r) {
                const int m = m0 + (wy*4 + i)*16 + q*4 + r;
                Cb[(size_t)m * N + n] = acc[i][j][r];
            }
        }
}

// ---------------------------------------------------------------------------
extern "C" void kernel_launch(void* const* d_in, const int* in_sizes, int n_in,
                              void* d_out, int out_size, void* d_ws, size_t ws_size,
                              hipStream_t stream)
{
    const float* audio = (const float*)d_in[0];   // [16,1024,512]
    const float* video = (const float*)d_in[1];   // [16, 512,512]
    const float* W     = (const float*)d_in[2];   // [512,512]
    const float* bias  = (const float*)d_in[3];   // [512]

    float* out_aligned = (float*)d_out;
    float* out_score   = (float*)d_out + (size_t)B_DIM * A_DIM * D_DIM;

    const size_t NA = (size_t)B_DIM * A_DIM * D_DIM;   // 8.39M
    const size_t NV = (size_t)B_DIM * V_DIM * D_DIM;   // 4.19M
    const size_t NS = (size_t)B_DIM * A_DIM * V_DIM;   // 8.39M

    float* ws = (float*)d_ws;
    float*          a_p  = ws;                                 // NA fp32 [dead after rownorm-a]
    float*          v_p  = a_p + NA;                           // NV fp32
    float*          sim  = v_p + NV;                           // NS fp32
    unsigned short* abf  = (unsigned short*)(sim + NS);        // NA bf16 [dead after proj-a]
    unsigned short* vbf  = (unsigned short*)(sim + NS) + NA;   // NV bf16 [dead after proj-v]
    unsigned short* v_nb = vbf + NV;                           // NV bf16
    unsigned short* Wbf  = v_nb + NV;                          // 262144 bf16
    unsigned short* a_nb = (unsigned short*)v_p;               // NA bf16 reuses v_p
    unsigned short* Pbf  = abf;                                // NS bf16 reuses dead abf
    unsigned short* vTb  = vbf;                                // NV bf16 reuses dead vbf
    float*          skew = a_p;                                // NS fp32 reuses dead a_p

    // 1) fp32 -> bf16 input conversions, one merged launch
    {
        const int nb_a = (int)(NA / 8 / 256);             // 4096
        const int nb_v = (int)(NV / 8 / 256);             // 2048
        const int nb_w = D_DIM * D_DIM / 8 / 256;         // 128
        cvt3_bf16_kernel<<<dim3(nb_a + nb_v + nb_w), dim3(256), 0, stream>>>(
            audio, abf, nb_a, video, vbf, nb_v, W, Wbf);
    }

    // 2) projections: X @ W^T + b
    gemm_bf16_nt<<<dim3(D_DIM/128, (B_DIM*A_DIM)/128, 1), dim3(256), 0, stream>>>(
        abf, Wbf, bias, a_p, B_DIM*A_DIM, D_DIM, D_DIM, 0, 0, 0);
    gemm_bf16_nt<<<dim3(D_DIM/128, (B_DIM*V_DIM)/128, 1), dim3(256), 0, stream>>>(
        vbf, Wbf, bias, v_p, B_DIM*V_DIM, D_DIM, D_DIM, 0, 0, 0);

    // 3) normalize -> bf16 (v first: frees v_p for a_nb)
    rownorm_cvt_kernel<<<dim3((B_DIM*V_DIM)/4), dim3(256), 0, stream>>>(v_p, v_nb);
    rownorm_cvt_kernel<<<dim3((B_DIM*A_DIM)/4), dim3(256), 0, stream>>>(a_p, a_nb);

    // 4) sim[b] = a_n[b] @ v_n[b]^T
    gemm_bf16_nt<<<dim3(V_DIM/128, A_DIM/128, B_DIM), dim3(256), 0, stream>>>(
        a_nb, v_nb, nullptr, sim, A_DIM, V_DIM, D_DIM,
        (size_t)A_DIM*D_DIM, (size_t)V_DIM*D_DIM, (size_t)A_DIM*V_DIM);

    // 5) video -> vT bf16 (independent of sim)
    transpose_cvt_kernel<<<dim3(D_DIM/32, V_DIM/32, B_DIM), dim3(256), 0, stream>>>(video, vTb);

    // 6) fused row softmax -> Pbf + skewed raw-sim copy for wavefront DTW
    softmax_skew_kernel<<<dim3((B_DIM*A_DIM)/4), dim3(256), 0, stream>>>(sim, Pbf, skew);

    // 7) fused PV GEMM + 256-lane wavefront DTW (DTW blocks first)
    pv_dtw_kernel<<<dim3(16 + (D_DIM/128)*(A_DIM/128)*B_DIM), dim3(256), 0, stream>>>(
        Pbf, vTb, skew, out_aligned, out_score);
}

// Round 5
// 324.617 us; speedup vs baseline: 1.4491x; 1.4491x over previous
//
#include <hip/hip_runtime.h>
#include <math.h>

#define B_DIM 16
#define A_DIM 1024
#define V_DIM 512
#define D_DIM 512
#define NEGV  (-1e30f)

typedef short bf16x8 __attribute__((ext_vector_type(8)));
typedef float floatx4 __attribute__((ext_vector_type(4)));

// round-to-nearest-even fp32 -> bf16
__device__ __forceinline__ short bf16_rne(float f) {
    unsigned u = __float_as_uint(f);
    return (short)((u + 0x7fffu + ((u >> 16) & 1u)) >> 16);
}

__device__ __forceinline__ float max3f(float a, float b, float c) {
    float d;
    asm("v_max3_f32 %0, %1, %2, %3" : "=v"(d) : "v"(a), "v"(b), "v"(c));
    return d;
}

// ---------------------------------------------------------------------------
// Merged elementwise fp32 -> bf16 for three segments (8 elems/thread).
// ---------------------------------------------------------------------------
__global__ __launch_bounds__(256) void cvt3_bf16_kernel(
    const float* __restrict__ in0, unsigned short* __restrict__ out0, int nb0,
    const float* __restrict__ in1, unsigned short* __restrict__ out1, int nb1,
    const float* __restrict__ in2, unsigned short* __restrict__ out2)
{
    int blk = blockIdx.x;
    const float* in; unsigned short* out;
    if (blk < nb0)              { in = in0; out = out0; }
    else if (blk < nb0 + nb1)   { in = in1; out = out1; blk -= nb0; }
    else                        { in = in2; out = out2; blk -= nb0 + nb1; }
    const int i = blk * 256 + threadIdx.x;
    float4 u = ((const float4*)in)[2*i];
    float4 v = ((const float4*)in)[2*i + 1];
    bf16x8 h;
    h[0]=bf16_rne(u.x); h[1]=bf16_rne(u.y); h[2]=bf16_rne(u.z); h[3]=bf16_rne(u.w);
    h[4]=bf16_rne(v.x); h[5]=bf16_rne(v.y); h[6]=bf16_rne(v.z); h[7]=bf16_rne(v.w);
    *(bf16x8*)(out + (size_t)i * 8) = h;
}

// ---------------------------------------------------------------------------
// bf16 MFMA NT GEMM with register-prefetch K-pipeline. 128x128 tile, BK=32.
// ---------------------------------------------------------------------------
__global__ __launch_bounds__(256) void gemm_bf16_nt(
    const unsigned short* __restrict__ Ag, const unsigned short* __restrict__ Bg,
    const float* __restrict__ bias, float* __restrict__ Cg,
    int M, int N, int K, size_t strA, size_t strB, size_t strC)
{
    __shared__ __align__(16) unsigned short lA[8*64*8];   // 8 KB
    __shared__ __align__(16) unsigned short lB[8*64*8];

    const unsigned short* Ab = Ag + (size_t)blockIdx.z * strA;
    const unsigned short* Bb = Bg + (size_t)blockIdx.z * strB;
    float*                Cb = Cg + (size_t)blockIdx.z * strC;

    const int m0 = blockIdx.y * 128;
    const int n0 = blockIdx.x * 128;
    const int tid = threadIdx.x, lane = tid & 63;
    const int w = tid >> 6, wy = w >> 1, wx = w & 1;

    const int u0 = tid, u1 = tid + 256;
    const int r_u0 = ((u0 >> 6) << 4) + (u0 & 15), k_u0 = ((u0 >> 4) & 3) * 8;
    const int r_u1 = ((u1 >> 6) << 4) + (u1 & 15), k_u1 = ((u1 >> 4) & 3) * 8;

    const unsigned short* gA0 = Ab + (size_t)(m0 + r_u0) * K + k_u0;
    const unsigned short* gA1 = Ab + (size_t)(m0 + r_u1) * K + k_u1;
    const unsigned short* gB0 = Bb + (size_t)(n0 + r_u0) * K + k_u0;
    const unsigned short* gB1 = Bb + (size_t)(n0 + r_u1) * K + k_u1;

    floatx4 acc[4][4];
    #pragma unroll
    for (int i = 0; i < 4; ++i)
        #pragma unroll
        for (int j = 0; j < 4; ++j) acc[i][j] = (floatx4){0.f, 0.f, 0.f, 0.f};

    bf16x8 a0 = *(const bf16x8*)(gA0);
    bf16x8 a1 = *(const bf16x8*)(gA1);
    bf16x8 b0 = *(const bf16x8*)(gB0);
    bf16x8 b1 = *(const bf16x8*)(gB1);

    for (int k0 = 0; k0 < K; k0 += 32) {
        __syncthreads();
        *(bf16x8*)&lA[(size_t)u0 * 8] = a0;
        *(bf16x8*)&lA[(size_t)u1 * 8] = a1;
        *(bf16x8*)&lB[(size_t)u0 * 8] = b0;
        *(bf16x8*)&lB[(size_t)u1 * 8] = b1;
        __syncthreads();

        if (k0 + 32 < K) {
            a0 = *(const bf16x8*)(gA0 + k0 + 32);
            a1 = *(const bf16x8*)(gA1 + k0 + 32);
            b0 = *(const bf16x8*)(gB0 + k0 + 32);
            b1 = *(const bf16x8*)(gB1 + k0 + 32);
        }

        bf16x8 fa[4], fb[4];
        #pragma unroll
        for (int t = 0; t < 4; ++t) {
            fa[t] = *(const bf16x8*)&lA[(((wy*4 + t)*64) + lane) * 8];
            fb[t] = *(const bf16x8*)&lB[(((wx*4 + t)*64) + lane) * 8];
        }
        #pragma unroll
        for (int i = 0; i < 4; ++i)
            #pragma unroll
            for (int j = 0; j < 4; ++j)
                acc[i][j] = __builtin_amdgcn_mfma_f32_16x16x32_bf16(fa[i], fb[j], acc[i][j], 0, 0, 0);
    }

    const int q = lane >> 4, c = lane & 15;
    #pragma unroll
    for (int i = 0; i < 4; ++i)
        #pragma unroll
        for (int j = 0; j < 4; ++j) {
            const int n = n0 + (wx*4 + j)*16 + c;
            const float bv = bias ? bias[n] : 0.f;
            #pragma unroll
            for (int r = 0; r < 4; ++r) {
                const int m = m0 + (wy*4 + i)*16 + q*4 + r;
                Cb[(size_t)m * N + n] = acc[i][j][r] + bv;
            }
        }
}

// ---------------------------------------------------------------------------
// Row L2-normalize fp32 -> bf16. One wave/row (512 cols).
// ---------------------------------------------------------------------------
__global__ __launch_bounds__(256) void rownorm_cvt_kernel(
    const float* __restrict__ in, unsigned short* __restrict__ out)
{
    const int wave = threadIdx.x >> 6;
    const int lane = threadIdx.x & 63;
    const size_t r = (size_t)blockIdx.x * 4 + wave;
    const float* p = in + r * D_DIM + lane * 8;
    float4 u = *(const float4*)p;
    float4 w = *(const float4*)(p + 4);
    float ss = u.x*u.x + u.y*u.y + u.z*u.z + u.w*u.w
             + w.x*w.x + w.y*w.y + w.z*w.z + w.w*w.w;
    #pragma unroll
    for (int m = 1; m < 64; m <<= 1) ss += __shfl_xor(ss, m, 64);
    const float inv = 1.0f / fmaxf(sqrtf(ss), 1e-12f);
    bf16x8 h;
    h[0]=bf16_rne(u.x*inv); h[1]=bf16_rne(u.y*inv); h[2]=bf16_rne(u.z*inv); h[3]=bf16_rne(u.w*inv);
    h[4]=bf16_rne(w.x*inv); h[5]=bf16_rne(w.y*inv); h[6]=bf16_rne(w.z*inv); h[7]=bf16_rne(w.w*inv);
    *(bf16x8*)(out + r * D_DIM + lane * 8) = h;
}

// ---------------------------------------------------------------------------
// DPP helper (wave64). 0x138 = wave_shr:1 (lane l <- l-1; lane 0 keeps oldv
// with bound_ctrl=false). Verified in prior rounds.
// ---------------------------------------------------------------------------
template <int CTRL, int RMASK>
__device__ __forceinline__ float fdpp(float oldv, float src) {
    int r = __builtin_amdgcn_update_dpp(
        __float_as_int(oldv), __float_as_int(src), CTRL, RMASK, 0xF, false);
    return __int_as_float(r);
}

// ---------------------------------------------------------------------------
// Fused: row softmax -> Pbf (bf16) + skewed fp32 copy of the raw sim row.
// DTW systolic lane g (4 rows/lane) has offset(g) = (g&63) + 72*(g>>6);
// skew[r][(c + sh) & 511] = sim[r][c] with sh = offset(g(r)) makes the DTW
// read column lane-uniform (phys index = step & 511).
// ---------------------------------------------------------------------------
__global__ __launch_bounds__(256) void softmax_skew_kernel(
    const float* __restrict__ sim, unsigned short* __restrict__ Pbf,
    float* __restrict__ skew)
{
    const int wave = threadIdx.x >> 6;
    const int lane = threadIdx.x & 63;
    const size_t r = (size_t)blockIdx.x * 4 + wave;
    const float* p = sim + r * V_DIM + lane * 8;
    float4 u = *(const float4*)p;
    float4 w = *(const float4*)(p + 4);
    float s[8] = {u.x,u.y,u.z,u.w,w.x,w.y,w.z,w.w};

    float m = s[0];
    #pragma unroll
    for (int k = 1; k < 8; ++k) m = fmaxf(m, s[k]);
    #pragma unroll
    for (int t = 1; t < 64; t <<= 1) m = fmaxf(m, __shfl_xor(m, t, 64));

    const float L2E = 1.44269504f;
    float ex[8];
    float e = 0.f;
    #pragma unroll
    for (int k = 0; k < 8; ++k) { ex[k] = exp2f((s[k] - m) * L2E); e += ex[k]; }
    #pragma unroll
    for (int t = 1; t < 64; t <<= 1) e += __shfl_xor(e, t, 64);
    const float ri = 1.0f / e;

    bf16x8 h;
    #pragma unroll
    for (int k = 0; k < 8; ++k) h[k] = bf16_rne(ex[k] * ri);
    *(bf16x8*)(Pbf + r * V_DIM + lane * 8) = h;

    // skewed raw-sim copy; rotation row-uniform, writes contiguous mod 512
    const int g  = ((int)r & 1023) >> 2;
    const int sh = (g & 63) + 72 * (g >> 6);
    float* Sk = skew + r * V_DIM;
    const int base = lane * 8 + sh;
    #pragma unroll
    for (int k = 0; k < 8; ++k) Sk[(base + k) & 511] = s[k];
}

// ---------------------------------------------------------------------------
// Batched 32x32 transpose + cvt: video[b][v][d] fp32 -> vT[b][d][v] bf16.
// ---------------------------------------------------------------------------
__global__ __launch_bounds__(256) void transpose_cvt_kernel(
    const float* __restrict__ in, unsigned short* __restrict__ out)
{
    __shared__ float t[32][33];
    const int b = blockIdx.z;
    const int v0 = blockIdx.y * 32, d0 = blockIdx.x * 32;
    const int x = threadIdx.x & 31, y0 = (threadIdx.x >> 5) * 4;
    const float* I = in + ((size_t)b * V_DIM + v0) * D_DIM + d0;
    #pragma unroll
    for (int r = 0; r < 4; ++r) t[y0 + r][x] = I[(size_t)(y0 + r) * D_DIM + x];
    __syncthreads();
    unsigned short* O = out + ((size_t)b * D_DIM + d0) * V_DIM + v0;
    #pragma unroll
    for (int r = 0; r < 4; ++r) O[(size_t)(y0 + r) * V_DIM + x] = (unsigned short)bf16_rne(t[x][y0 + r]);
}

// ---------------------------------------------------------------------------
// Fused PV GEMM + 256-lane wavefront DTW with BATCHED barriers.
// DTW (blocks 0..15): 256-lane systolic, 4 rows/lane. Lane g offset
// off = (g&63) + 72*(g>>6): the extra 8-step lag per wave lets waves sync
// once per 8-step batch instead of per step. Boundary rows pass through
// per-wave 520-slot LDS column arrays: producer (lane 63) stashes 8 dp[3]
// in regs, writes once per batch; consumer reads its 8 fills as two aligned
// float4 right after the barrier (broadcast). Every slot written once ->
// no WAR hazard; NEG-prefill + dump slot 519 cover out-of-range columns
// (col-512 fill is only read for predicated-off cells).
// Raw s_barrier + lgkmcnt-only wait: global c-prefetch stays in flight.
// ---------------------------------------------------------------------------
__global__ __launch_bounds__(256) void pv_dtw_kernel(
    const unsigned short* __restrict__ Pbf, const unsigned short* __restrict__ vTb,
    const float* __restrict__ skew, float* __restrict__ out_aligned,
    float* __restrict__ out_score)
{
    __shared__ __align__(16) unsigned short lA[8*64*8];
    __shared__ __align__(16) unsigned short lB[8*64*8];

    if (blockIdx.x < 16) {
        // ---------------- DTW path (all 256 threads) ----------------
        const int b    = blockIdx.x;
        const int tid  = threadIdx.x;
        const int lane = tid & 63;
        const int wv   = tid >> 6;
        const int off  = lane + 72 * wv;

        float* bndAll = (float*)lA;                    // 3 x 520 floats (6.2 KB)
        float* bndP = bndAll + wv * 520;               // producer array (wv<3)
        const float* bndC = bndAll + (wv > 0 ? wv - 1 : 0) * 520;
        for (int i = tid; i < 3 * 520; i += 256) bndAll[i] = NEGV;
        __syncthreads();

        const float* R0 = skew + ((size_t)(b * 1024 + tid * 4)) * 512;
        const float* R1 = R0 + 512;
        const float* R2 = R0 + 1024;
        const float* R3 = R0 + 1536;

        float dp[4] = {NEGV, NEGV, NEGV, NEGV};
        float st[8];
        float upC = NEGV;
        float upL = (tid == 0) ? 0.0f : NEGV;

        float4 A0[4], A1[4], B0[4], B1[4];
        A0[0] = *(const float4*)(R0);      A1[0] = *(const float4*)(R0 + 4);
        A0[1] = *(const float4*)(R1);      A1[1] = *(const float4*)(R1 + 4);
        A0[2] = *(const float4*)(R2);      A1[2] = *(const float4*)(R2 + 4);
        A0[3] = *(const float4*)(R3);      A1[3] = *(const float4*)(R3 + 4);
        B0[0] = *(const float4*)(R0 + 8);  B1[0] = *(const float4*)(R0 + 12);
        B0[1] = *(const float4*)(R1 + 8);  B1[1] = *(const float4*)(R1 + 12);
        B0[2] = *(const float4*)(R2 + 8);  B1[2] = *(const float4*)(R2 + 12);
        B0[3] = *(const float4*)(R3 + 8);  B1[3] = *(const float4*)(R3 + 12);

// one systolic step (K = 0..7 compile-time). FK = fill for step sb+K+1.
#define DTW_STEP(K, CV0, CV1, CV2, CV3, FK)                                   \
        {                                                                     \
            const unsigned jj = (unsigned)(sb + (K) - off);                   \
            if (jj < 512u) {                                                  \
                float u = upC, g = upL, old, nd;                              \
                old = dp[0]; nd = (CV0) + max3f(u, dp[0], g); dp[0] = nd; g = old; u = nd; \
                old = dp[1]; nd = (CV1) + max3f(u, dp[1], g); dp[1] = nd; g = old; u = nd; \
                old = dp[2]; nd = (CV2) + max3f(u, dp[2], g); dp[2] = nd; g = old; u = nd; \
                old = dp[3]; nd = (CV3) + max3f(u, dp[3], g); dp[3] = nd;                  \
            }                                                                 \
            st[K] = dp[3];                                                    \
            upL = upC;                                                        \
            upC = fdpp<0x138, 0xF>((FK), dp[3]);                              \
        }

// one 8-step batch on buffers C0/C1, then refill them for sb+16 and barrier.
#define DTW_BATCH(C0, C1)                                                     \
        {                                                                     \
            float4 f0, f1;                                                    \
            const int ps = sb + 8 - 72 * wv;                                  \
            if (wv > 0 && ps >= 0 && ps <= 512) {                             \
                f0 = *(const float4*)&bndC[ps];                               \
                f1 = *(const float4*)&bndC[ps + 4];                           \
            } else {                                                          \
                f0 = make_float4(NEGV, NEGV, NEGV, NEGV); f1 = f0;            \
            }                                                                 \
            DTW_STEP(0, C0[0].x, C0[1].x, C0[2].x, C0[3].x, f0.x)             \
            DTW_STEP(1, C0[0].y, C0[1].y, C0[2].y, C0[3].y, f0.y)             \
            DTW_STEP(2, C0[0].z, C0[1].z, C0[2].z, C0[3].z, f0.z)             \
            DTW_STEP(3, C0[0].w, C0[1].w, C0[2].w, C0[3].w, f0.w)             \
            DTW_STEP(4, C1[0].x, C1[1].x, C1[2].x, C1[3].x, f1.x)             \
            DTW_STEP(5, C1[0].y, C1[1].y, C1[2].y, C1[3].y, f1.y)             \
            DTW_STEP(6, C1[0].z, C1[1].z, C1[2].z, C1[3].z, f1.z)             \
            DTW_STEP(7, C1[0].w, C1[1].w, C1[2].w, C1[3].w, f1.w)             \
            {                                                                 \
                const int o16 = (sb + 16) & 511;                              \
                C0[0] = *(const float4*)(R0 + o16); C1[0] = *(const float4*)(R0 + o16 + 4); \
                C0[1] = *(const float4*)(R1 + o16); C1[1] = *(const float4*)(R1 + o16 + 4); \
                C0[2] = *(const float4*)(R2 + o16); C1[2] = *(const float4*)(R2 + o16 + 4); \
                C0[3] = *(const float4*)(R3 + o16); C1[3] = *(const float4*)(R3 + o16 + 4); \
            }                                                                 \
            if (wv < 3 && lane == 63) {                                       \
                _Pragma("unroll")                                             \
                for (int k = 0; k < 8; ++k) {                                 \
                    const int jp = sb + k - 63 - 72 * wv;                     \
                    const int adr = ((unsigned)jp < 512u) ? (jp + 7) : 519;   \
                    bndP[adr] = st[k];                                        \
                }                                                             \
            }                                                                 \
            asm volatile("s_waitcnt lgkmcnt(0)" ::: "memory");                \
            __builtin_amdgcn_s_barrier();                                     \
            asm volatile("" ::: "memory");                                    \
        }

        #pragma unroll 1
        for (int bt = 0; bt < 100; bt += 2) {
            int sb = bt * 8;
            DTW_BATCH(A0, A1)
            sb += 8;
            DTW_BATCH(B0, B1)
        }
#undef DTW_BATCH
#undef DTW_STEP
        if (tid == 255) out_score[b] = dp[3];
        return;
    }

    // ---------------- PV GEMM path ----------------
    const int bid = blockIdx.x - 16;
    const int n0 = (bid & 3) * 128;          // D/128 = 4
    const int m0 = ((bid >> 2) & 7) * 128;   // A/128 = 8
    const int bz = bid >> 5;                 // 16 batches
    const int K = V_DIM, N = D_DIM;

    const unsigned short* Ab = Pbf + (size_t)bz * A_DIM * V_DIM;
    const unsigned short* Bb = vTb + (size_t)bz * V_DIM * D_DIM;
    float*                Cb = out_aligned + (size_t)bz * A_DIM * D_DIM;

    const int tid = threadIdx.x, lane = tid & 63;
    const int w = tid >> 6, wy = w >> 1, wx = w & 1;
    const int u0 = tid, u1 = tid + 256;
    const int r_u0 = ((u0 >> 6) << 4) + (u0 & 15), k_u0 = ((u0 >> 4) & 3) * 8;
    const int r_u1 = ((u1 >> 6) << 4) + (u1 & 15), k_u1 = ((u1 >> 4) & 3) * 8;

    const unsigned short* gA0 = Ab + (size_t)(m0 + r_u0) * K + k_u0;
    const unsigned short* gA1 = Ab + (size_t)(m0 + r_u1) * K + k_u1;
    const unsigned short* gB0 = Bb + (size_t)(n0 + r_u0) * K + k_u0;
    const unsigned short* gB1 = Bb + (size_t)(n0 + r_u1) * K + k_u1;

    floatx4 acc[4][4];
    #pragma unroll
    for (int i = 0; i < 4; ++i)
        #pragma unroll
        for (int j = 0; j < 4; ++j) acc[i][j] = (floatx4){0.f, 0.f, 0.f, 0.f};

    bf16x8 a0 = *(const bf16x8*)(gA0);
    bf16x8 a1 = *(const bf16x8*)(gA1);
    bf16x8 b0 = *(const bf16x8*)(gB0);
    bf16x8 b1 = *(const bf16x8*)(gB1);

    for (int k0 = 0; k0 < K; k0 += 32) {
        __syncthreads();
        *(bf16x8*)&lA[(size_t)u0 * 8] = a0;
        *(bf16x8*)&lA[(size_t)u1 * 8] = a1;
        *(bf16x8*)&lB[(size_t)u0 * 8] = b0;
        *(bf16x8*)&lB[(size_t)u1 * 8] = b1;
        __syncthreads();
        if (k0 + 32 < K) {
            a0 = *(const bf16x8*)(gA0 + k0 + 32);
            a1 = *(const bf16x8*)(gA1 + k0 + 32);
            b0 = *(const bf16x8*)(gB0 + k0 + 32);
            b1 = *(const bf16x8*)(gB1 + k0 + 32);
        }
        bf16x8 fa[4], fb[4];
        #pragma unroll
        for (int t = 0; t < 4; ++t) {
            fa[t] = *(const bf16x8*)&lA[(((wy*4 + t)*64) + lane) * 8];
            fb[t] = *(const bf16x8*)&lB[(((wx*4 + t)*64) + lane) * 8];
        }
        #pragma unroll
        for (int i = 0; i < 4; ++i)
            #pragma unroll
            for (int j = 0; j < 4; ++j)
                acc[i][j] = __builtin_amdgcn_mfma_f32_16x16x32_bf16(fa[i], fb[j], acc[i][j], 0, 0, 0);
    }

    const int q = lane >> 4, c = lane & 15;
    #pragma unroll
    for (int i = 0; i < 4; ++i)
        #pragma unroll
        for (int j = 0; j < 4; ++j) {
            const int n = n0 + (wx*4 + j)*16 + c;
            #pragma unroll
            for (int r = 0; r < 4; ++r) {
                const int m = m0 + (wy*4 + i)*16 + q*4 + r;
                Cb[(size_t)m * N + n] = acc[i][j][r];
            }
        }
}

// ---------------------------------------------------------------------------
extern "C" void kernel_launch(void* const* d_in, const int* in_sizes, int n_in,
                              void* d_out, int out_size, void* d_ws, size_t ws_size,
                              hipStream_t stream)
{
    const float* audio = (const float*)d_in[0];   // [16,1024,512]
    const float* video = (const float*)d_in[1];   // [16, 512,512]
    const float* W     = (const float*)d_in[2];   // [512,512]
    const float* bias  = (const float*)d_in[3];   // [512]

    float* out_aligned = (float*)d_out;
    float* out_score   = (float*)d_out + (size_t)B_DIM * A_DIM * D_DIM;

    const size_t NA = (size_t)B_DIM * A_DIM * D_DIM;   // 8.39M
    const size_t NV = (size_t)B_DIM * V_DIM * D_DIM;   // 4.19M
    const size_t NS = (size_t)B_DIM * A_DIM * V_DIM;   // 8.39M

    float* ws = (float*)d_ws;
    float*          a_p  = ws;                                 // NA fp32 [dead after rownorm-a]
    float*          v_p  = a_p + NA;                           // NV fp32
    float*          sim  = v_p + NV;                           // NS fp32
    unsigned short* abf  = (unsigned short*)(sim + NS);        // NA bf16 [dead after proj-a]
    unsigned short* vbf  = (unsigned short*)(sim + NS) + NA;   // NV bf16 [dead after proj-v]
    unsigned short* v_nb = vbf + NV;                           // NV bf16
    unsigned short* Wbf  = v_nb + NV;                          // 262144 bf16
    unsigned short* a_nb = (unsigned short*)v_p;               // NA bf16 reuses v_p
    unsigned short* Pbf  = abf;                                // NS bf16 reuses dead abf
    unsigned short* vTb  = vbf;                                // NV bf16 reuses dead vbf
    float*          skew = a_p;                                // NS fp32 reuses dead a_p

    // 1) fp32 -> bf16 input conversions, one merged launch
    {
        const int nb_a = (int)(NA / 8 / 256);             // 4096
        const int nb_v = (int)(NV / 8 / 256);             // 2048
        const int nb_w = D_DIM * D_DIM / 8 / 256;         // 128
        cvt3_bf16_kernel<<<dim3(nb_a + nb_v + nb_w), dim3(256), 0, stream>>>(
            audio, abf, nb_a, video, vbf, nb_v, W, Wbf);
    }

    // 2) projections: X @ W^T + b
    gemm_bf16_nt<<<dim3(D_DIM/128, (B_DIM*A_DIM)/128, 1), dim3(256), 0, stream>>>(
        abf, Wbf, bias, a_p, B_DIM*A_DIM, D_DIM, D_DIM, 0, 0, 0);
    gemm_bf16_nt<<<dim3(D_DIM/128, (B_DIM*V_DIM)/128, 1), dim3(256), 0, stream>>>(
        vbf, Wbf, bias, v_p, B_DIM*V_DIM, D_DIM, D_DIM, 0, 0, 0);

    // 3) normalize -> bf16 (v first: frees v_p for a_nb)
    rownorm_cvt_kernel<<<dim3((B_DIM*V_DIM)/4), dim3(256), 0, stream>>>(v_p, v_nb);
    rownorm_cvt_kernel<<<dim3((B_DIM*A_DIM)/4), dim3(256), 0, stream>>>(a_p, a_nb);

    // 4) sim[b] = a_n[b] @ v_n[b]^T
    gemm_bf16_nt<<<dim3(V_DIM/128, A_DIM/128, B_DIM), dim3(256), 0, stream>>>(
        a_nb, v_nb, nullptr, sim, A_DIM, V_DIM, D_DIM,
        (size_t)A_DIM*D_DIM, (size_t)V_DIM*D_DIM, (size_t)A_DIM*V_DIM);

    // 5) video -> vT bf16 (independent of sim)
    transpose_cvt_kernel<<<dim3(D_DIM/32, V_DIM/32, B_DIM), dim3(256), 0, stream>>>(video, vTb);

    // 6) fused row softmax -> Pbf + skewed raw-sim copy for wavefront DTW
    softmax_skew_kernel<<<dim3((B_DIM*A_DIM)/4), dim3(256), 0, stream>>>(sim, Pbf, skew);

    // 7) fused PV GEMM + 256-lane batched-barrier wavefront DTW
    pv_dtw_kernel<<<dim3(16 + (D_DIM/128)*(A_DIM/128)*B_DIM), dim3(256), 0, stream>>>(
        Pbf, vTb, skew, out_aligned, out_score);
}